// Round 3
// baseline (367.663 us; speedup 1.0000x reference)
//
#include <hip/hip_runtime.h>

static constexpr int Tn = 2000;
static constexpr int Bn = 512;
static constexpr int Cn = 29;
static constexpr int Ln = 150;
static constexpr float LOG2E_F = 1.4426950408889634f;
static constexpr float LN2_F   = 0.6931471805599453f;
static constexpr float NEGV    = -1e30f;

// workspace layout (floats)
static constexpr int WS_DEN_F = 0;                      // 512*32
static constexpr int WS_DEN_B = 512 * 32;               // 512*32
static constexpr int WS_NUM_F = 2 * 512 * 32;           // 512*160
static constexpr int WS_NUM_B = 2 * 512 * 32 + 512 * 160;

#if __has_builtin(__builtin_amdgcn_exp2f)
#define FEXP2(x) __builtin_amdgcn_exp2f(x)
#else
#define FEXP2(x) exp2f(x)
#endif
#if __has_builtin(__builtin_amdgcn_logf)
#define FLOG2(x) __builtin_amdgcn_logf(x)
#else
#define FLOG2(x) log2f(x)
#endif

// 2^e for e in [-126, 127], exact
__device__ __forceinline__ float pow2i(int e) {
    return __int_as_float((e + 127) << 23);
}
// floor(log2(x)) for normal positive x
__device__ __forceinline__ int exp_of(float x) {
    return ((__float_as_int(x) >> 23) & 255) - 127;
}

__global__ __launch_bounds__(64)
void asg_scan(const float* __restrict__ inp, const float* __restrict__ tr,
              const int* __restrict__ tg, float* __restrict__ ws)
{
    const int tid = threadIdx.x;
    const int bid = blockIdx.x;
    __shared__ float wbuf[64];

    if (bid < 512) {
        // ================= DENOMINATOR (linear domain) =================
        // 2 groups of 32 lanes per wave; group = (dir, b); lane i = state.
        const int g   = tid >> 5;
        const int i   = tid & 31;
        const int gid = (bid << 1) | g;     // 0..1023
        const int dir = gid >> 9;           // 0 = fwd, 1 = bwd
        const int b   = gid & 511;
        const int ii  = (i < Cn) ? i : (Cn - 1);

        // E = exp(trans): fwd lane i holds row i; bwd lane j holds column j.
        float E[Cn];
#pragma unroll
        for (int j = 0; j < Cn; ++j) {
            float tv = dir ? tr[(1 + j) * Cn + ii] : tr[(1 + ii) * Cn + j];
            E[j] = FEXP2(LOG2E_F * tv);
        }

        float w;                 // linear state (w = 2^(log2e*alpha - Sacc))
        float Sacc = 0.f;        // accumulated log2 scale
        if (dir == 0)
            w = (i < Cn) ? FEXP2(LOG2E_F * (inp[(size_t)b * Cn + i] + tr[i])) : 0.f;
        else
            w = (i < Cn) ? 1.0f : 0.f;

        const float* eb = inp + (size_t)b * Cn + ii;
        const int t0    = dir ? (Tn - 1) : 1;
        const int dt    = dir ? -1 : 1;
        const int steps = dir ? 1000 : 999;

        // prefetch pipeline: cu = 2^(log2e*e) for current 8 steps (pad lanes -> 0),
        // ld = raw e for next block.
        float cu[8], ld[8];
#pragma unroll
        for (int u = 0; u < 8; ++u) {
            int tt = t0 + u * dt; tt = max(0, min(Tn - 1, tt));
            float r = eb[(size_t)tt * (Bn * Cn)];
            cu[u] = (i < Cn) ? FEXP2(LOG2E_F * r) : 0.f;
        }
#pragma unroll
        for (int u = 0; u < 8; ++u) {
            int tt = t0 + (8 + u) * dt; tt = max(0, min(Tn - 1, tt));
            ld[u] = eb[(size_t)tt * (Bn * Cn)];
        }
        const float* wb = &wbuf[g << 5];

        for (int s = 0; s < steps; s += 8) {
            float nl[8];
#pragma unroll
            for (int u = 0; u < 8; ++u) {       // issue loads 2 blocks ahead
                int tt = t0 + (s + 16 + u) * dt; tt = max(0, min(Tn - 1, tt));
                nl[u] = eb[(size_t)tt * (Bn * Cn)];
            }
#pragma unroll
            for (int u = 0; u < 8; ++u) {
                if (s + u < steps) {            // uniform branch
                    float share = dir ? (w * cu[u]) : w;   // bwd: pre-mul by u
                    wbuf[tid] = share;
                    __asm__ volatile("s_waitcnt lgkmcnt(0)" ::: "memory");
                    __builtin_amdgcn_sched_barrier(0);
                    const float4* wb4 = reinterpret_cast<const float4*>(wb);
                    float a0 = 0.f, a1 = 0.f, a2 = 0.f, a3 = 0.f;
                    float mx = 0.f;
#pragma unroll
                    for (int q = 0; q < 8; ++q) {
                        float4 wq = wb4[q];
                        a0 = fmaf(wq.x, E[4 * q + 0], a0);
                        mx = fmaxf(mx, fmaxf(fmaxf(wq.x, wq.y), fmaxf(wq.z, wq.w)));
                        if (q < 7) {
                            a1 = fmaf(wq.y, E[4 * q + 1], a1);
                            a2 = fmaf(wq.z, E[4 * q + 2], a2);
                            a3 = fmaf(wq.w, E[4 * q + 3], a3);
                        }
                    }
                    float dotv = (a0 + a1) + (a2 + a3);
                    int   gx   = exp_of(mx);            // mx > 0 always (positive matrix)
                    float nw   = dir ? dotv : dotv * cu[u];
                    w = ldexpf(nw, -gx);
                    Sacc += (float)gx;
                }
            }
#pragma unroll
            for (int u = 0; u < 8; ++u)         // exp2 for block s+8 (loads arrived)
                cu[u] = (i < Cn) ? FEXP2(LOG2E_F * ld[u]) : 0.f;
#pragma unroll
            for (int u = 0; u < 8; ++u) ld[u] = nl[u];
        }
        if (i < Cn)
            ws[(dir ? WS_DEN_B : WS_DEN_F) + b * 32 + i] = FLOG2(w) + Sacc;
    } else {
        // ================= NUMERATOR (linear domain, per-lane pow2 scales) ======
        // 1 wave = one (dir, b); lane k owns labels l = 3k..3k+2 (k < 50 active).
        const int nid = bid - 512;
        const int dir = nid >> 9;
        const int b   = nid & 511;
        const int k   = tid;
        const int* tb = tg + b * Ln;

        const int l0 = 3 * k, l1 = 3 * k + 1, l2 = 3 * k + 2;
        const int t0i = (l0 < Ln) ? tb[l0] : 0;
        const int t1i = (l1 < Ln) ? tb[l1] : 0;
        const int t2i = (l2 < Ln) ? tb[l2] : 0;
        const float S0 = FEXP2(LOG2E_F * tr[(1 + t0i) * Cn + t0i]);
        const float S1 = FEXP2(LOG2E_F * tr[(1 + t1i) * Cn + t1i]);
        const float S2 = FEXP2(LOG2E_F * tr[(1 + t2i) * Cn + t2i]);
        const int   p0 = (l0 >= 1 && l0 < Ln) ? tb[l0 - 1] : 0;
        const float M0 = (l0 >= 1 && l0 < Ln) ? FEXP2(LOG2E_F * tr[(1 + t0i) * Cn + p0]) : 1.0f;
        const float M1 = FEXP2(LOG2E_F * tr[(1 + t1i) * Cn + t0i]);
        const float M2 = FEXP2(LOG2E_F * tr[(1 + t2i) * Cn + t1i]);

        float w0 = 0.f, w1 = 0.f, w2 = 0.f;
        if (dir == 0) {
            if (k == 0) w0 = FEXP2(LOG2E_F * (tr[t0i] + inp[(size_t)b * Cn + t0i]));
        } else {
            if (k == 49) w2 = 1.0f;
        }
        int   sE  = 0;            // per-lane scale exponent (log2)
        float m0x = M0;           // fwd: M0 * 2^(s_{k-1}-s_k)
        float fdn = 1.0f;         // bwd: 2^(s_{k+1}-s_k)
        int   pgx = 0, psp = 0;   // pending renorm: own gx, neighbor prospective scale

        const int kk = (k < Cn) ? k : (Cn - 1);
        const float* eb = inp + (size_t)b * Cn + kk;  // lane k holds row value k
        const int t0    = dir ? (Tn - 1) : 1;
        const int dt    = dir ? -1 : 1;
        const int steps = dir ? 1000 : 999;

        // ue pipeline: ue* = exp(e_y) for the current 8 steps; nr/nr2 raw rows ahead.
        float ue0[8], ue1[8], ue2[8], nr[8], nr2[8];
#pragma unroll
        for (int u = 0; u < 8; ++u) {
            int tt = t0 + u * dt; tt = max(0, min(Tn - 1, tt));
            float r = eb[(size_t)tt * (Bn * Cn)];
            ue0[u] = FEXP2(LOG2E_F * __shfl(r, t0i));
            ue1[u] = FEXP2(LOG2E_F * __shfl(r, t1i));
            ue2[u] = FEXP2(LOG2E_F * __shfl(r, t2i));
        }
#pragma unroll
        for (int u = 0; u < 8; ++u) {
            int tt = t0 + (8 + u) * dt; tt = max(0, min(Tn - 1, tt));
            nr[u] = eb[(size_t)tt * (Bn * Cn)];
        }
#pragma unroll
        for (int u = 0; u < 8; ++u) {
            int tt = t0 + (16 + u) * dt; tt = max(0, min(Tn - 1, tt));
            nr2[u] = eb[(size_t)tt * (Bn * Cn)];
        }

        for (int s = 0; s < steps; s += 8) {
            float nl[8];
#pragma unroll
            for (int u = 0; u < 8; ++u) {       // loads 3 blocks ahead
                int tt = t0 + (s + 24 + u) * dt; tt = max(0, min(Tn - 1, tt));
                nl[u] = eb[(size_t)tt * (Bn * Cn)];
            }
#pragma unroll
            for (int u = 0; u < 8; ++u) {
                if (s + u < steps) {
                    // apply pending renorm (measured 2 steps ago; shuffle latency hidden)
                    if (u == 1 || u == 5) {
                        w0 = ldexpf(w0, -pgx);
                        w1 = ldexpf(w1, -pgx);
                        w2 = ldexpf(w2, -pgx);
                        sE += pgx;
                        int df = psp - sE;
                        df = max(-126, min(56, df));
                        float fx = pow2i(df);
                        m0x = M0 * fx;
                        fdn = fx;
                    }
                    // gather raw e for next block's u (background, off critical path)
                    float g0 = __shfl(nr[u], t0i);
                    float g1 = __shfl(nr[u], t1i);
                    float g2 = __shfl(nr[u], t2i);
                    if (dir == 0) {
                        float sh = __shfl_up(w2, 1);
                        sh = (k == 0) ? 0.f : sh;
                        float n0 = ue0[u] * fmaf(w0, S0, sh * m0x);
                        float n1 = ue1[u] * fmaf(w1, S1, w0 * M1);
                        float n2 = ue2[u] * fmaf(w2, S2, w1 * M2);
                        w0 = n0; w1 = n1; w2 = n2;
                    } else {
                        float q0 = w0 * ue0[u], q1 = w1 * ue1[u], q2 = w2 * ue2[u];
                        float mv = q0 * M0;
                        float mn = __shfl_down(mv, 1);
                        mn = (k == 49) ? 0.f : mn;
                        w0 = fmaf(q0, S0, q1 * M1);
                        w1 = fmaf(q1, S1, q2 * M2);
                        w2 = fmaf(q2, S2, mn * fdn);
                    }
                    ue0[u] = FEXP2(LOG2E_F * g0);
                    ue1[u] = FEXP2(LOG2E_F * g1);
                    ue2[u] = FEXP2(LOG2E_F * g2);
                    // measure renorm + launch neighbor-scale shuffle
                    if (u == 3 || u == 7) {
                        float mxn = fmaxf(fmaxf(w0, w1), w2);
                        pgx = (mxn > 0.f) ? exp_of(mxn) : 0;
                        int sp = sE + pgx;
                        psp = dir ? __shfl_down(sp, 1) : __shfl_up(sp, 1);
                    }
                }
            }
#pragma unroll
            for (int u = 0; u < 8; ++u) nr[u] = nr2[u];
#pragma unroll
            for (int u = 0; u < 8; ++u) nr2[u] = nl[u];
        }
        const int base = (dir ? WS_NUM_B : WS_NUM_F) + b * 160;
        if (l0 < Ln)     ws[base + l0]     = (w0 > 0.f) ? FLOG2(w0) + (float)sE : NEGV;
        if (l0 + 1 < Ln) ws[base + l0 + 1] = (w1 > 0.f) ? FLOG2(w1) + (float)sE : NEGV;
        if (l0 + 2 < Ln) ws[base + l0 + 2] = (w2 > 0.f) ? FLOG2(w2) + (float)sE : NEGV;
    }
}

__global__ __launch_bounds__(512)
void asg_combine(const float* __restrict__ ws, float* __restrict__ out)
{
    __shared__ float red[512];
    const int b = threadIdx.x;

    const float* f  = ws + WS_DEN_F + b * 32;
    const float* bk = ws + WS_DEN_B + b * 32;
    float vm = -3.0e38f;
#pragma unroll
    for (int i = 0; i < Cn; ++i) vm = fmaxf(vm, f[i] + bk[i]);
    float sum = 0.f;
#pragma unroll
    for (int i = 0; i < Cn; ++i) sum += FEXP2(f[i] + bk[i] - vm);
    float ld = vm + FLOG2(sum);

    const float* nf = ws + WS_NUM_F + b * 160;
    const float* nb = ws + WS_NUM_B + b * 160;
    float vm2 = -3.0e38f;
    for (int l = 0; l < Ln; ++l) vm2 = fmaxf(vm2, nf[l] + nb[l]);
    float sum2 = 0.f;
    for (int l = 0; l < Ln; ++l) sum2 += FEXP2(nf[l] + nb[l] - vm2);
    float ln = vm2 + FLOG2(sum2);

    red[b] = ld - ln;
    __syncthreads();
    for (int off = 256; off > 0; off >>= 1) {
        if (b < off) red[b] += red[b + off];
        __syncthreads();
    }
    if (b == 0) out[0] = red[0] * (LN2_F / 512.0f);
}

extern "C" void kernel_launch(void* const* d_in, const int* in_sizes, int n_in,
                              void* d_out, int out_size, void* d_ws, size_t ws_size,
                              hipStream_t stream)
{
    const float* inp = (const float*)d_in[0];
    const float* tr  = (const float*)d_in[1];
    const int*   tg  = (const int*)d_in[2];
    float* out = (float*)d_out;
    float* ws  = (float*)d_ws;

    hipLaunchKernelGGL(asg_scan,    dim3(1536), dim3(64),  0, stream, inp, tr, tg, ws);
    hipLaunchKernelGGL(asg_combine, dim3(1),    dim3(512), 0, stream, ws, out);
}